// Round 7
// baseline (335.179 us; speedup 1.0000x reference)
//
#include <hip/hip_runtime.h>
#include <cstdint>

// ---------------- workspace layout (float offsets) ----------------
#define WS_U      0                          // 3*8*512 = 12288
#define WS_C0     12288                      // 24 (unused now)
#define WS_ENTBM  12312                      // 1
#define WS_ENTP   12320                      // 8*512 = 4096
#define WS_P      16416                      // 1536*4096 = 6291456
#define WS_OUT2   WS_P                       // alias (P dead after vout GEMM)
#define WS_GPRE   (WS_P + 786432)            // 3 partials * 262144
#define WS_HFUSED (WS_P + 1572864)           // 262144
#define WS_ENHPRE (WS_P + 1835008)           // 2 partials * 262144
#define WS_VOUT   (WS_P + 6291456)           // 786432
#define WS_HCAT   (WS_VOUT + 786432)         // 786432
#define WS_H      (WS_HCAT + 786432)         // 1536
#define WS_Z      (WS_H + 1536)              // 1536

__device__ __forceinline__ float blk_sum4(float v, float* red, int lane, int wave) {
#pragma unroll
  for (int off = 32; off; off >>= 1) v += __shfl_xor(v, off);
  __syncthreads();
  if (lane == 0) red[wave] = v;
  __syncthreads();
  return red[0] + red[1] + red[2] + red[3];
}

// ---------------- prep: grid (4, 8); m<3 -> u vectors, m==3 -> ent partials ----------------
__global__ __launch_bounds__(256) void prep_kernel(
    const float* __restrict__ qrgb, const float* __restrict__ qnir, const float* __restrict__ qtir,
    const float* __restrict__ inw, const float* __restrict__ inb,
    const float* __restrict__ entw, const float* __restrict__ entb,
    float* __restrict__ ws)
{
  const int m = blockIdx.x, h = blockIdx.y;
  const int tid = threadIdx.x, lane = tid & 63, wave = tid >> 6;
  __shared__ float qvl[64];
  __shared__ float red[4];

  if (m == 3) {
    const float* base = entw + (size_t)h * 64 * 512;
    float acc0 = 0.f, acc1 = 0.f;
#pragma unroll 8
    for (int r = 0; r < 64; r++) {
      acc0 += base[(size_t)r * 512 + tid];
      acc1 += base[(size_t)r * 512 + tid + 256];
    }
    ws[WS_ENTP + h * 512 + tid] = acc0;
    ws[WS_ENTP + h * 512 + tid + 256] = acc1;
    return;
  }

  const float* qry = (m == 0) ? qrgb : (m == 1) ? qnir : qtir;
  float4 q0 = *(const float4*)(qry + 4 * lane);
  float4 q1 = *(const float4*)(qry + 256 + 4 * lane);
#pragma unroll 4
  for (int dd = 0; dd < 16; dd++) {
    const int d = wave * 16 + dd;
    const float* wr = inw + (size_t)(h * 64 + d) * 512;
    float4 w0 = *(const float4*)(wr + 4 * lane);
    float4 w1 = *(const float4*)(wr + 256 + 4 * lane);
    float p = w0.x * q0.x + w0.y * q0.y + w0.z * q0.z + w0.w * q0.w
            + w1.x * q1.x + w1.y * q1.y + w1.z * q1.z + w1.w * q1.w;
#pragma unroll
    for (int off = 32; off; off >>= 1) p += __shfl_xor(p, off);
    if (lane == 0) qvl[d] = p + inb[h * 64 + d];
  }
  __syncthreads();
  float acc0 = 0.f, acc1 = 0.f;
  const float* wk = inw + (size_t)(512 + h * 64) * 512;
#pragma unroll 8
  for (int d = 0; d < 64; d++) {
    float qq = qvl[d];
    acc0 = fmaf(qq, wk[(size_t)d * 512 + tid], acc0);
    acc1 = fmaf(qq, wk[(size_t)d * 512 + tid + 256], acc1);
  }
  ws[WS_U + m * 4096 + h * 512 + tid] = 0.125f * acc0;
  ws[WS_U + m * 4096 + h * 512 + tid + 256] = 0.125f * acc1;
  if (m == 0 && h == 0) {
    float v = entb[tid] + entb[tid + 256];
    float s = blk_sum4(v, red, lane, wave);
    if (tid == 0) ws[WS_ENTBM] = s * (1.f / 512.f);
  }
}

// ---------------- attn scores: R6 phase S (verified butterfly) + softmax ----------------
// Writes normalized weights w[h][132-padded] into the PREFIX of this block's P row
// (WS_P + (m*512+b)*4096). The pool kernel consumes then overwrites that row.
__global__ __launch_bounds__(256) void attn_score_kernel(
    const float* __restrict__ trgb, const float* __restrict__ tnir, const float* __restrict__ ttir,
    const float* __restrict__ ws, float* __restrict__ Pout)
{
  const int b = blockIdx.x, m = blockIdx.y;
  const int tid = threadIdx.x, lane = tid & 63, wave = tid >> 6;
  const float* tok = ((m == 0) ? trgb : (m == 1) ? tnir : ttir) + (size_t)b * 129 * 512;
  const float* u = ws + WS_U + m * 4096;

  __shared__ float sc[8][132];        // raw scores

  const int b0 = lane & 1, b1 = (lane >> 1) & 1, b2 = (lane >> 2) & 1;
  const int b3 = (lane >> 3) & 1, b4 = (lane >> 4) & 1;
  const int r_own = (b0 << 1) | b1;
  const int h_own = (b2 << 2) | (b3 << 1) | b4;
  const int wbase = wave * 32;

#define LOADB(L0, A0, C0, A1, C1, A2, C2, A3, C3)                         \
  do {                                                                    \
    int r0_ = (L0), r1_ = (L0) + 1, r2_ = (L0) + 2, r3_ = (L0) + 3;       \
    if (r1_ > 128) r1_ = 128;                                             \
    if (r2_ > 128) r2_ = 128;                                             \
    if (r3_ > 128) r3_ = 128;                                             \
    const float* p0_ = tok + (size_t)r0_ * 512 + 4 * lane;                \
    const float* p1_ = tok + (size_t)r1_ * 512 + 4 * lane;                \
    const float* p2_ = tok + (size_t)r2_ * 512 + 4 * lane;                \
    const float* p3_ = tok + (size_t)r3_ * 512 + 4 * lane;                \
    A0 = *(const float4*)p0_; C0 = *(const float4*)(p0_ + 256);           \
    A1 = *(const float4*)p1_; C1 = *(const float4*)(p1_ + 256);           \
    A2 = *(const float4*)p2_; C2 = *(const float4*)(p2_ + 256);           \
    A3 = *(const float4*)p3_; C3 = *(const float4*)(p3_ + 256);           \
  } while (0)

  auto score_batch = [&](int l0, bool tail,
                         float4 A0, float4 C0, float4 A1, float4 C1,
                         float4 A2, float4 C2, float4 A3, float4 C3) {
    float x[32];
#pragma unroll
    for (int h = 0; h < 8; h++) {
      float4 U0 = *(const float4*)(u + h * 512 + 4 * lane);
      float4 U1 = *(const float4*)(u + h * 512 + 256 + 4 * lane);
      x[h]      = A0.x * U0.x + A0.y * U0.y + A0.z * U0.z + A0.w * U0.w
                + C0.x * U1.x + C0.y * U1.y + C0.z * U1.z + C0.w * U1.w;
      x[8 + h]  = A1.x * U0.x + A1.y * U0.y + A1.z * U0.z + A1.w * U0.w
                + C1.x * U1.x + C1.y * U1.y + C1.z * U1.z + C1.w * U1.w;
      x[16 + h] = A2.x * U0.x + A2.y * U0.y + A2.z * U0.z + A2.w * U0.w
                + C2.x * U1.x + C2.y * U1.y + C2.z * U1.z + C2.w * U1.w;
      x[24 + h] = A3.x * U0.x + A3.y * U0.y + A3.z * U0.z + A3.w * U0.w
                + C3.x * U1.x + C3.y * U1.y + C3.z * U1.z + C3.w * U1.w;
    }
#define MERGE_STAGE(n, M, bit)                                  \
    _Pragma("unroll")                                           \
    for (int j = 0; j < (n) / 2; j++) {                         \
      float keep = (bit) ? x[j + (n) / 2] : x[j];               \
      float send = (bit) ? x[j] : x[j + (n) / 2];               \
      x[j] = keep + __shfl_xor(send, (M));                      \
    }
    MERGE_STAGE(32, 1, b0)
    MERGE_STAGE(16, 2, b1)
    MERGE_STAGE(8, 4, b2)
    MERGE_STAGE(4, 8, b3)
    MERGE_STAGE(2, 16, b4)
#undef MERGE_STAGE
    float T = x[0] + __shfl_xor(x[0], 32);
    if (lane < 32 && (!tail || r_own == 0))
      sc[h_own][l0 + r_own] = T;
  };

  {
    float4 A0, C0, A1, C1, A2, C2, A3, C3;
    float4 N0, D0, N1, D1, N2, D2, N3, D3;
    LOADB(wbase, A0, C0, A1, C1, A2, C2, A3, C3);
    for (int bt = 0; bt < 8; bt++) {
      if (bt < 7) LOADB(wbase + 4 * bt + 4, N0, D0, N1, D1, N2, D2, N3, D3);
      score_batch(wbase + 4 * bt, false, A0, C0, A1, C1, A2, C2, A3, C3);
      A0 = N0; C0 = D0; A1 = N1; C1 = D1;
      A2 = N2; C2 = D2; A3 = N3; C3 = D3;
    }
    if (wave == 0) {
      LOADB(128, A0, C0, A1, C1, A2, C2, A3, C3);
      score_batch(128, true, A0, C0, A1, C1, A2, C2, A3, C3);
    }
  }
#undef LOADB
  __syncthreads();

  // softmax over 129 per head (verified), write normalized weights to global
  float* wout = Pout + (size_t)(m * 512 + b) * 4096;
#pragma unroll
  for (int hh = 0; hh < 2; hh++) {
    const int h = wave * 2 + hh;
    float x0 = sc[h][lane];
    float x1 = sc[h][64 + lane];
    float x2 = (lane == 0) ? sc[h][128] : -3.0e38f;
    float mx = fmaxf(fmaxf(x0, x1), x2);
#pragma unroll
    for (int off = 32; off; off >>= 1) mx = fmaxf(mx, __shfl_xor(mx, off));
    float e0 = __expf(x0 - mx), e1 = __expf(x1 - mx);
    float e2 = (lane == 0) ? __expf(x2 - mx) : 0.f;
    float s = e0 + e1 + e2;
#pragma unroll
    for (int off = 32; off; off >>= 1) s += __shfl_xor(s, off);
    float inv = 1.f / s;
    wout[h * 132 + lane] = e0 * inv;
    wout[h * 132 + 64 + lane] = e1 * inv;
    if (lane == 0) wout[h * 132 + 128] = e2 * inv;
  }
}

// ---------------- attn pooling: pure streaming, wave owns 2 heads x all rows ----------------
// acc = 4 float4 (16 regs), depth-4 named-register row ring, no cross-wave combine.
// Reads the weight prefix from its P row into LDS, then overwrites the row with P.
__global__ __launch_bounds__(256) void attn_pool_kernel(
    const float* __restrict__ trgb, const float* __restrict__ tnir, const float* __restrict__ ttir,
    float* __restrict__ Pout)
{
  const int b = blockIdx.x, m = blockIdx.y;
  const int tid = threadIdx.x, lane = tid & 63, wave = tid >> 6;
  const float* tok = ((m == 0) ? trgb : (m == 1) ? tnir : ttir) + (size_t)b * 129 * 512;
  float* prow = Pout + (size_t)(m * 512 + b) * 4096;

  __shared__ float sc[8][132];
  // weights -> LDS (1056 floats; tail slots unused garbage, never read)
  for (int i = tid; i < 1056; i += 256) ((float*)sc)[i] = prow[i];
  __syncthreads();

  const int h0 = wave * 2, h1 = h0 + 1;
  float4 acc00 = make_float4(0.f, 0.f, 0.f, 0.f);
  float4 acc01 = make_float4(0.f, 0.f, 0.f, 0.f);
  float4 acc10 = make_float4(0.f, 0.f, 0.f, 0.f);
  float4 acc11 = make_float4(0.f, 0.f, 0.f, 0.f);

#define LDROW(rr, Av, Cv)                                         \
  do {                                                            \
    const float* p_ = tok + (size_t)(rr) * 512 + 4 * lane;        \
    Av = *(const float4*)p_; Cv = *(const float4*)(p_ + 256);     \
  } while (0)

#define POOLR(Av, Cv, l)                                          \
  do {                                                            \
    float w0_ = sc[h0][l], w1_ = sc[h1][l];                       \
    acc00.x = fmaf(w0_, Av.x, acc00.x);                           \
    acc00.y = fmaf(w0_, Av.y, acc00.y);                           \
    acc00.z = fmaf(w0_, Av.z, acc00.z);                           \
    acc00.w = fmaf(w0_, Av.w, acc00.w);                           \
    acc01.x = fmaf(w0_, Cv.x, acc01.x);                           \
    acc01.y = fmaf(w0_, Cv.y, acc01.y);                           \
    acc01.z = fmaf(w0_, Cv.z, acc01.z);                           \
    acc01.w = fmaf(w0_, Cv.w, acc01.w);                           \
    acc10.x = fmaf(w1_, Av.x, acc10.x);                           \
    acc10.y = fmaf(w1_, Av.y, acc10.y);                           \
    acc10.z = fmaf(w1_, Av.z, acc10.z);                           \
    acc10.w = fmaf(w1_, Av.w, acc10.w);                           \
    acc11.x = fmaf(w1_, Cv.x, acc11.x);                           \
    acc11.y = fmaf(w1_, Cv.y, acc11.y);                           \
    acc11.z = fmaf(w1_, Cv.z, acc11.z);                           \
    acc11.w = fmaf(w1_, Cv.w, acc11.w);                           \
  } while (0)

  float4 A0, C0, A1, C1, A2, C2, A3, C3;
  LDROW(0, A0, C0); LDROW(1, A1, C1); LDROW(2, A2, C2); LDROW(3, A3, C3);
  for (int g = 0; g < 32; g++) {
    const int rb = 4 * g;
    int rr;
    POOLR(A0, C0, rb);
    rr = rb + 4; if (rr > 128) rr = 128; LDROW(rr, A0, C0);
    POOLR(A1, C1, rb + 1);
    rr = rb + 5; if (rr > 128) rr = 128; LDROW(rr, A1, C1);
    POOLR(A2, C2, rb + 2);
    rr = rb + 6; if (rr > 128) rr = 128; LDROW(rr, A2, C2);
    POOLR(A3, C3, rb + 3);
    rr = rb + 7; if (rr > 128) rr = 128; LDROW(rr, A3, C3);
  }
  POOLR(A0, C0, 128);   // A0 holds row 128 (loaded at g=31, stage 0)
#undef LDROW
#undef POOLR

  // store: wave writes its 2 heads directly (overwrites consumed weight prefix)
  *(float4*)(prow + h0 * 512 + 4 * lane) = acc00;
  *(float4*)(prow + h0 * 512 + 256 + 4 * lane) = acc01;
  *(float4*)(prow + h1 * 512 + 4 * lane) = acc10;
  *(float4*)(prow + h1 * 512 + 256 + 4 * lane) = acc11;
}

// ---------------- f32 GEMM: C = A @ B^T (+bias), 64x64 tile, 4x4 micro ----------------
__global__ __launch_bounds__(256) void gemm_bt_kernel(
    const float* __restrict__ A, const float* __restrict__ B,
    const float* __restrict__ bias, float* __restrict__ C,
    int K, int lda, int ldb, int ldc,
    long sA, long sB, long sC, int sBias, int addBias)
{
  A += (long)blockIdx.z * sA;
  B += (long)blockIdx.z * sB;
  C += (long)blockIdx.z * sC;
  const float* bp = bias + (long)blockIdx.z * sBias;
  __shared__ float As[32][68];
  __shared__ float Bs[32][68];
  const int tid = threadIdx.x;
  const int tx = tid & 15, ty = tid >> 4;
  const int rowL = tid >> 3;
  const int colv = (tid & 7) << 2;
  const int m0 = blockIdx.x * 64, n0 = blockIdx.y * 64;
  float acc[4][4] = {};
  for (int k0 = 0; k0 < K; k0 += 32) {
#pragma unroll
    for (int it = 0; it < 2; it++) {
      const int r = rowL + it * 32;
      float4 v = *(const float4*)(A + (size_t)(m0 + r) * lda + k0 + colv);
      As[colv + 0][r] = v.x; As[colv + 1][r] = v.y; As[colv + 2][r] = v.z; As[colv + 3][r] = v.w;
      float4 w = *(const float4*)(B + (size_t)(n0 + r) * ldb + k0 + colv);
      Bs[colv + 0][r] = w.x; Bs[colv + 1][r] = w.y; Bs[colv + 2][r] = w.z; Bs[colv + 3][r] = w.w;
    }
    __syncthreads();
#pragma unroll
    for (int k = 0; k < 32; k++) {
      float4 a4 = *(const float4*)&As[k][ty * 4];
      float4 b4 = *(const float4*)&Bs[k][tx * 4];
      acc[0][0] += a4.x * b4.x; acc[0][1] += a4.x * b4.y; acc[0][2] += a4.x * b4.z; acc[0][3] += a4.x * b4.w;
      acc[1][0] += a4.y * b4.x; acc[1][1] += a4.y * b4.y; acc[1][2] += a4.y * b4.z; acc[1][3] += a4.y * b4.w;
      acc[2][0] += a4.z * b4.x; acc[2][1] += a4.z * b4.y; acc[2][2] += a4.z * b4.z; acc[2][3] += a4.z * b4.w;
      acc[3][0] += a4.w * b4.x; acc[3][1] += a4.w * b4.y; acc[3][2] += a4.w * b4.z; acc[3][3] += a4.w * b4.w;
    }
    __syncthreads();
  }
  float4 bv = make_float4(0.f, 0.f, 0.f, 0.f);
  if (addBias) bv = *(const float4*)(bp + n0 + tx * 4);
#pragma unroll
  for (int i = 0; i < 4; i++) {
    float4 o;
    o.x = acc[i][0] + bv.x; o.y = acc[i][1] + bv.y;
    o.z = acc[i][2] + bv.z; o.w = acc[i][3] + bv.w;
    *(float4*)(C + (size_t)(m0 + ty * 4 + i) * ldc + n0 + tx * 4) = o;
  }
}

// ---------------- LN(attn out) + entropy + z ----------------
__global__ __launch_bounds__(256) void ln_ent_kernel(
    const float* __restrict__ out2,
    const float* __restrict__ lng, const float* __restrict__ lnb,
    const float* __restrict__ ws, float* __restrict__ hcat,
    float* __restrict__ Hout, float* __restrict__ zout)
{
  const int r = blockIdx.x;
  const int mod = r >> 9, b = r & 511;
  const int tid = threadIdx.x, lane = tid & 63, wave = tid >> 6;
  __shared__ float red[4];
  const float* x = out2 + (size_t)r * 512;
  float2 v = *(const float2*)(x + 2 * tid);
  float s = blk_sum4(v.x + v.y, red, lane, wave);
  float sq = blk_sum4(v.x * v.x + v.y * v.y, red, lane, wave);
  float mean = s * (1.f / 512.f);
  float var = sq * (1.f / 512.f) - mean * mean;
  float rstd = rsqrtf(var + 1e-5f);
  float2 g = *(const float2*)(lng + 2 * tid);
  float2 bb = *(const float2*)(lnb + 2 * tid);
  float h0 = (v.x - mean) * rstd * g.x + bb.x;
  float h1 = (v.y - mean) * rstd * g.y + bb.y;
  *(float2*)(hcat + (size_t)b * 1536 + mod * 512 + 2 * tid) = make_float2(h0, h1);
  float2 ep = make_float2(0.f, 0.f);
#pragma unroll
  for (int j = 0; j < 8; j++) {
    float2 t = *(const float2*)(ws + WS_ENTP + j * 512 + 2 * tid);
    ep.x += t.x; ep.y += t.y;
  }
  ep.x *= (1.f / 512.f); ep.y *= (1.f / 512.f);
  float fa0 = fabsf(h0) + 1e-8f, fa1 = fabsf(h1) + 1e-8f;
  float S = blk_sum4(fa0 + fa1, red, lane, wave);
  float zz = blk_sum4(h0 * ep.x + h1 * ep.y, red, lane, wave);
  float invS = 1.f / S;
  float p0 = fa0 * invS, p1 = fa1 * invS;
  float t = blk_sum4(p0 * logf(p0 + 1e-8f) + p1 * logf(p1 + 1e-8f), red, lane, wave);
  if (tid == 0) {
    Hout[mod * 512 + b] = -t;
    zout[mod * 512 + b] = zz + ws[WS_ENTBM];
  }
}

// ---------------- gate LN/relu/sigmoid + entropy softmax + fuse ----------------
__global__ __launch_bounds__(256) void gate_fuse_kernel(
    const float* __restrict__ gpre, const float* __restrict__ glng, const float* __restrict__ glnb,
    const float* __restrict__ gw2, const float* __restrict__ gb2, const float* __restrict__ gb1,
    const float* __restrict__ araw, const float* __restrict__ hcat,
    const float* __restrict__ H, const float* __restrict__ z,
    float* __restrict__ hfused)
{
  const int b = blockIdx.x;
  const int tid = threadIdx.x, lane = tid & 63, wave = tid >> 6;
  __shared__ float red[4];
  float2 v;
  {
    float2 p0 = *(const float2*)(gpre + (size_t)b * 512 + 2 * tid);
    float2 p1 = *(const float2*)(gpre + 262144 + (size_t)b * 512 + 2 * tid);
    float2 p2 = *(const float2*)(gpre + 524288 + (size_t)b * 512 + 2 * tid);
    float2 bi = *(const float2*)(gb1 + 2 * tid);
    v.x = p0.x + p1.x + p2.x + bi.x;
    v.y = p0.y + p1.y + p2.y + bi.y;
  }
  float s = blk_sum4(v.x + v.y, red, lane, wave);
  float sq = blk_sum4(v.x * v.x + v.y * v.y, red, lane, wave);
  float mean = s * (1.f / 512.f), var = sq * (1.f / 512.f) - mean * mean;
  float rstd = rsqrtf(var + 1e-5f);
  float2 g = *(const float2*)(glng + 2 * tid);
  float2 bb = *(const float2*)(glnb + 2 * tid);
  float g0 = fmaxf((v.x - mean) * rstd * g.x + bb.x, 0.f);
  float g1 = fmaxf((v.y - mean) * rstd * g.y + bb.y, 0.f);
  float d0 = blk_sum4(g0 * gw2[2 * tid] + g1 * gw2[2 * tid + 1], red, lane, wave);
  float d1 = blk_sum4(g0 * gw2[512 + 2 * tid] + g1 * gw2[512 + 2 * tid + 1], red, lane, wave);
  float d2 = blk_sum4(g0 * gw2[1024 + 2 * tid] + g1 * gw2[1024 + 2 * tid + 1], red, lane, wave);
  float ga0 = 1.f / (1.f + __expf(-(d0 + gb2[0])));
  float ga1 = 1.f / (1.f + __expf(-(d1 + gb2[1])));
  float ga2 = 1.f / (1.f + __expf(-(d2 + gb2[2])));
  float sc0 = z[b] * __expf(-H[b]);
  float sc1 = z[512 + b] * __expf(-H[512 + b]);
  float sc2 = z[1024 + b] * __expf(-H[1024 + b]);
  float mxs = fmaxf(sc0, fmaxf(sc1, sc2));
  float e0 = __expf(sc0 - mxs), e1 = __expf(sc1 - mxs), e2 = __expf(sc2 - mxs);
  float inv = 1.f / (e0 + e1 + e2);
  e0 *= inv; e1 *= inv; e2 *= inv;
  float alpha = 1.f / (1.f + __expf(-araw[0]));
  const float* hb = hcat + (size_t)b * 1536 + 2 * tid;
  float2 hr = *(const float2*)hb;
  float2 hn = *(const float2*)(hb + 512);
  float2 ht = *(const float2*)(hb + 1024);
  float2 o;
  o.x = alpha * (e0 * hr.x + e1 * hn.x + e2 * ht.x)
      + (1.f - alpha) * (ga0 * hr.x + ga1 * hn.x + ga2 * ht.x);
  o.y = alpha * (e0 * hr.y + e1 * hn.y + e2 * ht.y)
      + (1.f - alpha) * (ga0 * hr.y + ga1 * hn.y + ga2 * ht.y);
  *(float2*)(hfused + (size_t)b * 512 + 2 * tid) = o;
}

// ---------------- final LN(enh) + concat-add ----------------
__global__ __launch_bounds__(256) void final_out_kernel(
    const float* __restrict__ epre, const float* __restrict__ enb,
    const float* __restrict__ elng, const float* __restrict__ elnb,
    const float* __restrict__ hcat, float* __restrict__ out)
{
  const int b = blockIdx.x;
  const int tid = threadIdx.x, lane = tid & 63, wave = tid >> 6;
  __shared__ float red[4];
  float2 v;
  {
    float2 p0 = *(const float2*)(epre + (size_t)b * 512 + 2 * tid);
    float2 p1 = *(const float2*)(epre + 262144 + (size_t)b * 512 + 2 * tid);
    float2 bi = *(const float2*)(enb + 2 * tid);
    v.x = p0.x + p1.x + bi.x;
    v.y = p0.y + p1.y + bi.y;
  }
  float s = blk_sum4(v.x + v.y, red, lane, wave);
  float sq = blk_sum4(v.x * v.x + v.y * v.y, red, lane, wave);
  float mean = s * (1.f / 512.f), var = sq * (1.f / 512.f) - mean * mean;
  float rstd = rsqrtf(var + 1e-5f);
  float2 g = *(const float2*)(elng + 2 * tid);
  float2 bb = *(const float2*)(elnb + 2 * tid);
  float e0 = (v.x - mean) * rstd * g.x + bb.x;
  float e1 = (v.y - mean) * rstd * g.y + bb.y;
  const float* hb = hcat + (size_t)b * 1536 + 2 * tid;
  float* ob = out + (size_t)b * 1536 + 2 * tid;
#pragma unroll
  for (int mm = 0; mm < 3; mm++) {
    float2 hv = *(const float2*)(hb + mm * 512);
    *(float2*)(ob + mm * 512) = make_float2(hv.x + e0, hv.y + e1);
  }
}

extern "C" void kernel_launch(void* const* d_in, const int* in_sizes, int n_in,
                              void* d_out, int out_size, void* d_ws, size_t ws_size,
                              hipStream_t stream)
{
  const float* trgb = (const float*)d_in[0];
  const float* tnir = (const float*)d_in[1];
  const float* ttir = (const float*)d_in[2];
  const float* qrgb = (const float*)d_in[3];
  const float* qnir = (const float*)d_in[4];
  const float* qtir = (const float*)d_in[5];
  const float* inw  = (const float*)d_in[6];
  const float* inb  = (const float*)d_in[7];
  const float* outw = (const float*)d_in[8];
  const float* outb = (const float*)d_in[9];
  const float* alng = (const float*)d_in[10];
  const float* alnb = (const float*)d_in[11];
  const float* entw = (const float*)d_in[12];
  const float* entb = (const float*)d_in[13];
  const float* gw1  = (const float*)d_in[14];
  const float* gb1  = (const float*)d_in[15];
  const float* glng = (const float*)d_in[16];
  const float* glnb = (const float*)d_in[17];
  const float* gw2  = (const float*)d_in[18];
  const float* gb2  = (const float*)d_in[19];
  const float* araw = (const float*)d_in[20];
  const float* enw  = (const float*)d_in[21];
  const float* enb  = (const float*)d_in[22];
  const float* elng = (const float*)d_in[23];
  const float* elnb = (const float*)d_in[24];
  float* ws = (float*)d_ws;
  float* out = (float*)d_out;

  hipLaunchKernelGGL(prep_kernel, dim3(4, 8), dim3(256), 0, stream,
                     qrgb, qnir, qtir, inw, inb, entw, entb, ws);
  hipLaunchKernelGGL(attn_score_kernel, dim3(512, 3), dim3(256), 0, stream,
                     trgb, tnir, ttir, ws, ws + WS_P);
  hipLaunchKernelGGL(attn_pool_kernel, dim3(512, 3), dim3(256), 0, stream,
                     trgb, tnir, ttir, ws + WS_P);
  // vout = P @ Wv^T + bv (batched over 8 heads)
  hipLaunchKernelGGL(gemm_bt_kernel, dim3(24, 1, 8), dim3(256), 0, stream,
                     ws + WS_P, inw + (size_t)1024 * 512, inb + 1024, ws + WS_VOUT,
                     512, 4096, 512, 512,
                     (long)512, (long)64 * 512, (long)64, 64, 1);
  // out2 = vout @ Wo^T + bo
  hipLaunchKernelGGL(gemm_bt_kernel, dim3(24, 8, 1), dim3(256), 0, stream,
                     ws + WS_VOUT, outw, outb, ws + WS_OUT2,
                     512, 512, 512, 512, 0L, 0L, 0L, 0, 1);
  hipLaunchKernelGGL(ln_ent_kernel, dim3(1536), dim3(256), 0, stream,
                     ws + WS_OUT2, alng, alnb, ws, ws + WS_HCAT, ws + WS_H, ws + WS_Z);
  // g_pre partials = hcat @ gate_w1^T (split-K x3, bias added in gate_fuse)
  hipLaunchKernelGGL(gemm_bt_kernel, dim3(8, 8, 3), dim3(256), 0, stream,
                     ws + WS_HCAT, gw1, gb1, ws + WS_GPRE,
                     512, 1536, 1536, 512,
                     (long)512, (long)512, (long)262144, 0, 0);
  hipLaunchKernelGGL(gate_fuse_kernel, dim3(512), dim3(256), 0, stream,
                     ws + WS_GPRE, glng, glnb, gw2, gb2, gb1, araw,
                     ws + WS_HCAT, ws + WS_H, ws + WS_Z, ws + WS_HFUSED);
  // enh partials = h_fused @ enh_w^T (split-K x2, bias added in final_out)
  hipLaunchKernelGGL(gemm_bt_kernel, dim3(8, 8, 2), dim3(256), 0, stream,
                     ws + WS_HFUSED, enw, enb, ws + WS_ENHPRE,
                     256, 512, 512, 512,
                     (long)256, (long)256, (long)262144, 0, 0);
  hipLaunchKernelGGL(final_out_kernel, dim3(512), dim3(256), 0, stream,
                     ws + WS_ENHPRE, enb, elng, elnb, ws + WS_HCAT, out);
}

// Round 8
// 294.932 us; speedup vs baseline: 1.1365x; 1.1365x over previous
//
#include <hip/hip_runtime.h>
#include <cstdint>

// ---------------- workspace layout (float offsets) ----------------
#define WS_U      0                          // 3*8*512 = 12288
#define WS_C0     12288                      // 24 (unused now)
#define WS_ENTBM  12312                      // 1
#define WS_ENTP   12320                      // 8*512 = 4096
#define WS_P      16416                      // 1536*4096 = 6291456
#define WS_OUT2   WS_P                       // alias (P dead after vout GEMM)
#define WS_GPRE   (WS_P + 786432)            // 3 partials * 262144
#define WS_HFUSED (WS_P + 1572864)           // 262144
#define WS_ENHPRE (WS_P + 1835008)           // 2 partials * 262144
#define WS_VOUT   (WS_P + 6291456)           // 786432
#define WS_HCAT   (WS_VOUT + 786432)         // 786432
#define WS_H      (WS_HCAT + 786432)         // 1536
#define WS_Z      (WS_H + 1536)              // 1536

__device__ __forceinline__ float blk_sum4(float v, float* red, int lane, int wave) {
#pragma unroll
  for (int off = 32; off; off >>= 1) v += __shfl_xor(v, off);
  __syncthreads();
  if (lane == 0) red[wave] = v;
  __syncthreads();
  return red[0] + red[1] + red[2] + red[3];
}

// ---------------- prep: grid (4, 8); m<3 -> u vectors, m==3 -> ent partials ----------------
__global__ __launch_bounds__(256) void prep_kernel(
    const float* __restrict__ qrgb, const float* __restrict__ qnir, const float* __restrict__ qtir,
    const float* __restrict__ inw, const float* __restrict__ inb,
    const float* __restrict__ entw, const float* __restrict__ entb,
    float* __restrict__ ws)
{
  const int m = blockIdx.x, h = blockIdx.y;
  const int tid = threadIdx.x, lane = tid & 63, wave = tid >> 6;
  __shared__ float qvl[64];
  __shared__ float red[4];

  if (m == 3) {
    const float* base = entw + (size_t)h * 64 * 512;
    float acc0 = 0.f, acc1 = 0.f;
#pragma unroll 8
    for (int r = 0; r < 64; r++) {
      acc0 += base[(size_t)r * 512 + tid];
      acc1 += base[(size_t)r * 512 + tid + 256];
    }
    ws[WS_ENTP + h * 512 + tid] = acc0;
    ws[WS_ENTP + h * 512 + tid + 256] = acc1;
    return;
  }

  const float* qry = (m == 0) ? qrgb : (m == 1) ? qnir : qtir;
  float4 q0 = *(const float4*)(qry + 4 * lane);
  float4 q1 = *(const float4*)(qry + 256 + 4 * lane);
#pragma unroll 4
  for (int dd = 0; dd < 16; dd++) {
    const int d = wave * 16 + dd;
    const float* wr = inw + (size_t)(h * 64 + d) * 512;
    float4 w0 = *(const float4*)(wr + 4 * lane);
    float4 w1 = *(const float4*)(wr + 256 + 4 * lane);
    float p = w0.x * q0.x + w0.y * q0.y + w0.z * q0.z + w0.w * q0.w
            + w1.x * q1.x + w1.y * q1.y + w1.z * q1.z + w1.w * q1.w;
#pragma unroll
    for (int off = 32; off; off >>= 1) p += __shfl_xor(p, off);
    if (lane == 0) qvl[d] = p + inb[h * 64 + d];
  }
  __syncthreads();
  float acc0 = 0.f, acc1 = 0.f;
  const float* wk = inw + (size_t)(512 + h * 64) * 512;
#pragma unroll 8
  for (int d = 0; d < 64; d++) {
    float qq = qvl[d];
    acc0 = fmaf(qq, wk[(size_t)d * 512 + tid], acc0);
    acc1 = fmaf(qq, wk[(size_t)d * 512 + tid + 256], acc1);
  }
  ws[WS_U + m * 4096 + h * 512 + tid] = 0.125f * acc0;
  ws[WS_U + m * 4096 + h * 512 + tid + 256] = 0.125f * acc1;
  if (m == 0 && h == 0) {
    float v = entb[tid] + entb[tid + 256];
    float s = blk_sum4(v, red, lane, wave);
    if (tid == 0) ws[WS_ENTBM] = s * (1.f / 512.f);
  }
}

// ---------------- attn_pool: single-pass, 4-row batched butterfly online softmax ----------------
// = R4's verified math (transpose-reduce butterfly, per-lane-own (m,s), deferred
// rescale, masked row-128 tail, fw-combine epilogue) re-expressed with R1/R7's
// spill-free codegen: NO launch_bounds cap, by-value float4 lambda params, static
// indexing only. One HBM pass (203 MB), one 6-deep chain + 1 exp + 1 LDS
// publish per 4 rows.
__global__ __launch_bounds__(256) void attn_pool_kernel(
    const float* __restrict__ trgb, const float* __restrict__ tnir, const float* __restrict__ ttir,
    const float* __restrict__ ws, float* __restrict__ Pout)
{
  const int b = blockIdx.x, m = blockIdx.y;
  const int tid = threadIdx.x, lane = tid & 63, wave = tid >> 6;
  const float* tok = ((m == 0) ? trgb : (m == 1) ? tnir : ttir) + (size_t)b * 129 * 512;
  const float* u = ws + WS_U + m * 4096;

  __shared__ float lacc[4][2][512];   // 16 KB combine stage (2 heads / round)
  __shared__ float lstat[4][16];      // per-wave m[8], s[8]
  __shared__ float wls[4][32];        // per-wave w[r*8+h] publish
  __shared__ float sls[4][8];         // per-wave scl[h] publish

  const int b0 = lane & 1, b1 = (lane >> 1) & 1, b2 = (lane >> 2) & 1;
  const int b3 = (lane >> 3) & 1, b4 = (lane >> 4) & 1;
  const int r_own = (b0 << 1) | b1;                 // row-in-batch this lane owns
  const int h_own = (b2 << 2) | (b3 << 1) | b4;     // head this lane owns
  const int wbase = wave * 32;

  float acc[8][8];
#pragma unroll
  for (int h = 0; h < 8; h++)
#pragma unroll
    for (int j = 0; j < 8; j++) acc[h][j] = 0.f;
  float m_own = 0.f, s_own = 0.f;

#define LOADB(L0, A0, C0, A1, C1, A2, C2, A3, C3)                         \
  do {                                                                    \
    int r0_ = (L0), r1_ = (L0) + 1, r2_ = (L0) + 2, r3_ = (L0) + 3;       \
    if (r1_ > 128) r1_ = 128;                                             \
    if (r2_ > 128) r2_ = 128;                                             \
    if (r3_ > 128) r3_ = 128;                                             \
    const float* p0_ = tok + (size_t)r0_ * 512 + 4 * lane;                \
    const float* p1_ = tok + (size_t)r1_ * 512 + 4 * lane;                \
    const float* p2_ = tok + (size_t)r2_ * 512 + 4 * lane;                \
    const float* p3_ = tok + (size_t)r3_ * 512 + 4 * lane;                \
    A0 = *(const float4*)p0_; C0 = *(const float4*)(p0_ + 256);           \
    A1 = *(const float4*)p1_; C1 = *(const float4*)(p1_ + 256);           \
    A2 = *(const float4*)p2_; C2 = *(const float4*)(p2_ + 256);           \
    A3 = *(const float4*)p3_; C3 = *(const float4*)(p3_ + 256);           \
  } while (0)

#define ACCH(H, W, Av, Cv)                                                \
  acc[H][0] = fmaf((W), Av.x, acc[H][0]);                                 \
  acc[H][1] = fmaf((W), Av.y, acc[H][1]);                                 \
  acc[H][2] = fmaf((W), Av.z, acc[H][2]);                                 \
  acc[H][3] = fmaf((W), Av.w, acc[H][3]);                                 \
  acc[H][4] = fmaf((W), Cv.x, acc[H][4]);                                 \
  acc[H][5] = fmaf((W), Cv.y, acc[H][5]);                                 \
  acc[H][6] = fmaf((W), Cv.z, acc[H][6]);                                 \
  acc[H][7] = fmaf((W), Cv.w, acc[H][7]);

#define ACCR(RIDX, Av, Cv)                                                \
  do {                                                                    \
    float4 wlo_ = *(const float4*)&wls[wave][(RIDX) * 8];                 \
    float4 whi_ = *(const float4*)&wls[wave][(RIDX) * 8 + 4];             \
    ACCH(0, wlo_.x, Av, Cv) ACCH(1, wlo_.y, Av, Cv)                       \
    ACCH(2, wlo_.z, Av, Cv) ACCH(3, wlo_.w, Av, Cv)                       \
    ACCH(4, whi_.x, Av, Cv) ACCH(5, whi_.y, Av, Cv)                       \
    ACCH(6, whi_.z, Av, Cv) ACCH(7, whi_.w, Av, Cv)                       \
  } while (0)

  // by-value float4 params (SROA-safe, R1/R7 precedent); acc/state captured by ref,
  // statically indexed only.
  auto body = [&](bool tail,
                  float4 A0, float4 C0, float4 A1, float4 C1,
                  float4 A2, float4 C2, float4 A3, float4 C3) {
    float x[32];
#pragma unroll
    for (int h = 0; h < 8; h++) {
      float4 U0 = *(const float4*)(u + h * 512 + 4 * lane);
      float4 U1 = *(const float4*)(u + h * 512 + 256 + 4 * lane);
      x[h]      = A0.x * U0.x + A0.y * U0.y + A0.z * U0.z + A0.w * U0.w
                + C0.x * U1.x + C0.y * U1.y + C0.z * U1.z + C0.w * U1.w;
      x[8 + h]  = A1.x * U0.x + A1.y * U0.y + A1.z * U0.z + A1.w * U0.w
                + C1.x * U1.x + C1.y * U1.y + C1.z * U1.z + C1.w * U1.w;
      x[16 + h] = A2.x * U0.x + A2.y * U0.y + A2.z * U0.z + A2.w * U0.w
                + C2.x * U1.x + C2.y * U1.y + C2.z * U1.z + C2.w * U1.w;
      x[24 + h] = A3.x * U0.x + A3.y * U0.y + A3.z * U0.z + A3.w * U0.w
                + C3.x * U1.x + C3.y * U1.y + C3.z * U1.z + C3.w * U1.w;
    }
    // transpose-reduce butterfly (verified R4/R6/R7): one 6-deep chain for all 32
#define MERGE_STAGE(n, M, bit)                                  \
    _Pragma("unroll")                                           \
    for (int j = 0; j < (n) / 2; j++) {                         \
      float keep = (bit) ? x[j + (n) / 2] : x[j];               \
      float send = (bit) ? x[j] : x[j + (n) / 2];               \
      x[j] = keep + __shfl_xor(send, (M));                      \
    }
    MERGE_STAGE(32, 1, b0)
    MERGE_STAGE(16, 2, b1)
    MERGE_STAGE(8, 4, b2)
    MERGE_STAGE(4, 8, b3)
    MERGE_STAGE(2, 16, b4)
#undef MERGE_STAGE
    float T = x[0] + __shfl_xor(x[0], 32);      // lane holds score of (r_own,h_own)
    if (tail && r_own != 0) T = -3.0e38f;       // only row 128 valid in tail batch
    // per-head batch max over the 4 rows (rows vary with lane bits 0,1)
    float mb = fmaxf(T, __shfl_xor(T, 1));
    mb = fmaxf(mb, __shfl_xor(mb, 2));
    // owner math: deferred rescale (thr 8, cold), ONE exp per lane per batch
    bool re = (mb > m_own + 8.f);
    float scl = __expf(re ? (m_own - mb) : 0.f);    // ==1 on hot path
    float mN = re ? mb : m_own;
    float w = __expf(T - mN);
    float sb = w + __shfl_xor(w, 1);
    sb += __shfl_xor(sb, 2);
    s_own = s_own * scl + sb;
    m_own = mN;
    if (lane < 32) {
      wls[wave][r_own * 8 + h_own] = w;
      if (r_own == 0) sls[wave][h_own] = scl;
    }
    // cold rescale of acc (wave-uniform branch)
    float4 sc0_ = *(const float4*)&sls[wave][0];
    float4 sc1_ = *(const float4*)&sls[wave][4];
    float smin = fminf(fminf(fminf(sc0_.x, sc0_.y), fminf(sc0_.z, sc0_.w)),
                       fminf(fminf(sc1_.x, sc1_.y), fminf(sc1_.z, sc1_.w)));
    if (smin < 1.f) {
      ACCH(0, 0.f, A0, C0)   // dummy no-op shape keeper removed below; real rescale:
#pragma unroll
      for (int h = 0; h < 8; h++) {
        float sv = (h < 4) ? ((h == 0) ? sc0_.x : (h == 1) ? sc0_.y : (h == 2) ? sc0_.z : sc0_.w)
                           : ((h == 4) ? sc1_.x : (h == 5) ? sc1_.y : (h == 6) ? sc1_.z : sc1_.w);
#pragma unroll
        for (int j = 0; j < 8; j++) acc[h][j] *= sv;
      }
    }
    // accumulate 4 rows x 8 heads from registers
    ACCR(0, A0, C0);
    ACCR(1, A1, C1);
    ACCR(2, A2, C2);
    ACCR(3, A3, C3);
  };

  {
    float4 A0, C0, A1, C1, A2, C2, A3, C3;
    float4 N0, D0, N1, D1, N2, D2, N3, D3;
    LOADB(wbase, A0, C0, A1, C1, A2, C2, A3, C3);
    for (int bt = 0; bt < 8; bt++) {
      if (bt < 7) LOADB(wbase + 4 * bt + 4, N0, D0, N1, D1, N2, D2, N3, D3);
      body(false, A0, C0, A1, C1, A2, C2, A3, C3);
      A0 = N0; C0 = D0; A1 = N1; C1 = D1;
      A2 = N2; C2 = D2; A3 = N3; C3 = D3;
    }
    if (wave == 0) {   // masked row-128 batch
      LOADB(128, A0, C0, A1, C1, A2, C2, A3, C3);
      body(true, A0, C0, A1, C1, A2, C2, A3, C3);
    }
  }
#undef LOADB
#undef ACCR
#undef ACCH

  // ---- cross-wave combine (verified R4 epilogue) ----
  if (lane < 32 && r_own == 0) {
    lstat[wave][h_own] = m_own;
    lstat[wave][8 + h_own] = s_own;
  }
  __syncthreads();
  float fw[4][8];
#pragma unroll
  for (int h = 0; h < 8; h++) {
    float m0 = lstat[0][h], m1 = lstat[1][h], m2 = lstat[2][h], m3 = lstat[3][h];
    float Mx = fmaxf(fmaxf(m0, m1), fmaxf(m2, m3));
    float f0 = __expf(m0 - Mx), f1 = __expf(m1 - Mx);
    float f2 = __expf(m2 - Mx), f3 = __expf(m3 - Mx);
    float S = lstat[0][8 + h] * f0 + lstat[1][8 + h] * f1
            + lstat[2][8 + h] * f2 + lstat[3][8 + h] * f3;
    float is = 1.f / S;
    fw[0][h] = f0 * is; fw[1][h] = f1 * is; fw[2][h] = f2 * is; fw[3][h] = f3 * is;
  }
  float* po = Pout + (size_t)(m * 512 + b) * 4096 + 2 * tid;
#pragma unroll
  for (int hb = 0; hb < 8; hb += 2) {
    __syncthreads();                  // previous round's reads (or main loop) done
#pragma unroll
    for (int hh = 0; hh < 2; hh++) {
      const int h = hb + hh;
      *(float4*)&lacc[wave][hh][4 * lane] =
          make_float4(acc[h][0], acc[h][1], acc[h][2], acc[h][3]);
      *(float4*)&lacc[wave][hh][256 + 4 * lane] =
          make_float4(acc[h][4], acc[h][5], acc[h][6], acc[h][7]);
    }
    __syncthreads();
#pragma unroll
    for (int hh = 0; hh < 2; hh++) {
      const int h = hb + hh;
      float2 x0 = *(const float2*)&lacc[0][hh][2 * tid];
      float2 x1 = *(const float2*)&lacc[1][hh][2 * tid];
      float2 x2 = *(const float2*)&lacc[2][hh][2 * tid];
      float2 x3 = *(const float2*)&lacc[3][hh][2 * tid];
      float ox = x0.x * fw[0][h] + x1.x * fw[1][h] + x2.x * fw[2][h] + x3.x * fw[3][h];
      float oy = x0.y * fw[0][h] + x1.y * fw[1][h] + x2.y * fw[2][h] + x3.y * fw[3][h];
      *(float2*)(po + h * 512) = make_float2(ox, oy);
    }
  }
}

// ---------------- f32 GEMM: C = A @ B^T (+bias), 64x64 tile, 4x4 micro ----------------
__global__ __launch_bounds__(256) void gemm_bt_kernel(
    const float* __restrict__ A, const float* __restrict__ B,
    const float* __restrict__ bias, float* __restrict__ C,
    int K, int lda, int ldb, int ldc,
    long sA, long sB, long sC, int sBias, int addBias)
{
  A += (long)blockIdx.z * sA;
  B += (long)blockIdx.z * sB;
  C += (long)blockIdx.z * sC;
  const float* bp = bias + (long)blockIdx.z * sBias;
  __shared__ float As[32][68];
  __shared__ float Bs[32][68];
  const int tid = threadIdx.x;
  const int tx = tid & 15, ty = tid >> 4;
  const int rowL = tid >> 3;
  const int colv = (tid & 7) << 2;
  const int m0 = blockIdx.x * 64, n0 = blockIdx.y * 64;
  float acc[4][4] = {};
  for (int k0 = 0; k0 < K; k0 += 32) {
#pragma unroll
    for (int it = 0; it < 2; it++) {
      const int r = rowL + it * 32;
      float4 v = *(const float4*)(A + (size_t)(m0 + r) * lda + k0 + colv);
      As[colv + 0][r] = v.x; As[colv + 1][r] = v.y; As[colv + 2][r] = v.z; As[colv + 3][r] = v.w;
      float4 w = *(const float4*)(B + (size_t)(n0 + r) * ldb + k0 + colv);
      Bs[colv + 0][r] = w.x; Bs[colv + 1][r] = w.y; Bs[colv + 2][r] = w.z; Bs[colv + 3][r] = w.w;
    }
    __syncthreads();
#pragma unroll
    for (int k = 0; k < 32; k++) {
      float4 a4 = *(const float4*)&As[k][ty * 4];
      float4 b4 = *(const float4*)&Bs[k][tx * 4];
      acc[0][0] += a4.x * b4.x; acc[0][1] += a4.x * b4.y; acc[0][2] += a4.x * b4.z; acc[0][3] += a4.x * b4.w;
      acc[1][0] += a4.y * b4.x; acc[1][1] += a4.y * b4.y; acc[1][2] += a4.y * b4.z; acc[1][3] += a4.y * b4.w;
      acc[2][0] += a4.z * b4.x; acc[2][1] += a4.z * b4.y; acc[2][2] += a4.z * b4.z; acc[2][3] += a4.z * b4.w;
      acc[3][0] += a4.w * b4.x; acc[3][1] += a4.w * b4.y; acc[3][2] += a4.w * b4.z; acc[3][3] += a4.w * b4.w;
    }
    __syncthreads();
  }
  float4 bv = make_float4(0.f, 0.f, 0.f, 0.f);
  if (addBias) bv = *(const float4*)(bp + n0 + tx * 4);
#pragma unroll
  for (int i = 0; i < 4; i++) {
    float4 o;
    o.x = acc[i][0] + bv.x; o.y = acc[i][1] + bv.y;
    o.z = acc[i][2] + bv.z; o.w = acc[i][3] + bv.w;
    *(float4*)(C + (size_t)(m0 + ty * 4 + i) * ldc + n0 + tx * 4) = o;
  }
}

// ---------------- LN(attn out) + entropy + z ----------------
__global__ __launch_bounds__(256) void ln_ent_kernel(
    const float* __restrict__ out2,
    const float* __restrict__ lng, const float* __restrict__ lnb,
    const float* __restrict__ ws, float* __restrict__ hcat,
    float* __restrict__ Hout, float* __restrict__ zout)
{
  const int r = blockIdx.x;
  const int mod = r >> 9, b = r & 511;
  const int tid = threadIdx.x, lane = tid & 63, wave = tid >> 6;
  __shared__ float red[4];
  const float* x = out2 + (size_t)r * 512;
  float2 v = *(const float2*)(x + 2 * tid);
  float s = blk_sum4(v.x + v.y, red, lane, wave);
  float sq = blk_sum4(v.x * v.x + v.y * v.y, red, lane, wave);
  float mean = s * (1.f / 512.f);
  float var = sq * (1.f / 512.f) - mean * mean;
  float rstd = rsqrtf(var + 1e-5f);
  float2 g = *(const float2*)(lng + 2 * tid);
  float2 bb = *(const float2*)(lnb + 2 * tid);
  float h0 = (v.x - mean) * rstd * g.x + bb.x;
  float h1 = (v.y - mean) * rstd * g.y + bb.y;
  *(float2*)(hcat + (size_t)b * 1536 + mod * 512 + 2 * tid) = make_float2(h0, h1);
  float2 ep = make_float2(0.f, 0.f);
#pragma unroll
  for (int j = 0; j < 8; j++) {
    float2 t = *(const float2*)(ws + WS_ENTP + j * 512 + 2 * tid);
    ep.x += t.x; ep.y += t.y;
  }
  ep.x *= (1.f / 512.f); ep.y *= (1.f / 512.f);
  float fa0 = fabsf(h0) + 1e-8f, fa1 = fabsf(h1) + 1e-8f;
  float S = blk_sum4(fa0 + fa1, red, lane, wave);
  float zz = blk_sum4(h0 * ep.x + h1 * ep.y, red, lane, wave);
  float invS = 1.f / S;
  float p0 = fa0 * invS, p1 = fa1 * invS;
  float t = blk_sum4(p0 * logf(p0 + 1e-8f) + p1 * logf(p1 + 1e-8f), red, lane, wave);
  if (tid == 0) {
    Hout[mod * 512 + b] = -t;
    zout[mod * 512 + b] = zz + ws[WS_ENTBM];
  }
}

// ---------------- gate LN/relu/sigmoid + entropy softmax + fuse ----------------
__global__ __launch_bounds__(256) void gate_fuse_kernel(
    const float* __restrict__ gpre, const float* __restrict__ glng, const float* __restrict__ glnb,
    const float* __restrict__ gw2, const float* __restrict__ gb2, const float* __restrict__ gb1,
    const float* __restrict__ araw, const float* __restrict__ hcat,
    const float* __restrict__ H, const float* __restrict__ z,
    float* __restrict__ hfused)
{
  const int b = blockIdx.x;
  const int tid = threadIdx.x, lane = tid & 63, wave = tid >> 6;
  __shared__ float red[4];
  float2 v;
  {
    float2 p0 = *(const float2*)(gpre + (size_t)b * 512 + 2 * tid);
    float2 p1 = *(const float2*)(gpre + 262144 + (size_t)b * 512 + 2 * tid);
    float2 p2 = *(const float2*)(gpre + 524288 + (size_t)b * 512 + 2 * tid);
    float2 bi = *(const float2*)(gb1 + 2 * tid);
    v.x = p0.x + p1.x + p2.x + bi.x;
    v.y = p0.y + p1.y + p2.y + bi.y;
  }
  float s = blk_sum4(v.x + v.y, red, lane, wave);
  float sq = blk_sum4(v.x * v.x + v.y * v.y, red, lane, wave);
  float mean = s * (1.f / 512.f), var = sq * (1.f / 512.f) - mean * mean;
  float rstd = rsqrtf(var + 1e-5f);
  float2 g = *(const float2*)(glng + 2 * tid);
  float2 bb = *(const float2*)(glnb + 2 * tid);
  float g0 = fmaxf((v.x - mean) * rstd * g.x + bb.x, 0.f);
  float g1 = fmaxf((v.y - mean) * rstd * g.y + bb.y, 0.f);
  float d0 = blk_sum4(g0 * gw2[2 * tid] + g1 * gw2[2 * tid + 1], red, lane, wave);
  float d1 = blk_sum4(g0 * gw2[512 + 2 * tid] + g1 * gw2[512 + 2 * tid + 1], red, lane, wave);
  float d2 = blk_sum4(g0 * gw2[1024 + 2 * tid] + g1 * gw2[1024 + 2 * tid + 1], red, lane, wave);
  float ga0 = 1.f / (1.f + __expf(-(d0 + gb2[0])));
  float ga1 = 1.f / (1.f + __expf(-(d1 + gb2[1])));
  float ga2 = 1.f / (1.f + __expf(-(d2 + gb2[2])));
  float sc0 = z[b] * __expf(-H[b]);
  float sc1 = z[512 + b] * __expf(-H[512 + b]);
  float sc2 = z[1024 + b] * __expf(-H[1024 + b]);
  float mxs = fmaxf(sc0, fmaxf(sc1, sc2));
  float e0 = __expf(sc0 - mxs), e1 = __expf(sc1 - mxs), e2 = __expf(sc2 - mxs);
  float inv = 1.f / (e0 + e1 + e2);
  e0 *= inv; e1 *= inv; e2 *= inv;
  float alpha = 1.f / (1.f + __expf(-araw[0]));
  const float* hb = hcat + (size_t)b * 1536 + 2 * tid;
  float2 hr = *(const float2*)hb;
  float2 hn = *(const float2*)(hb + 512);
  float2 ht = *(const float2*)(hb + 1024);
  float2 o;
  o.x = alpha * (e0 * hr.x + e1 * hn.x + e2 * ht.x)
      + (1.f - alpha) * (ga0 * hr.x + ga1 * hn.x + ga2 * ht.x);
  o.y = alpha * (e0 * hr.y + e1 * hn.y + e2 * ht.y)
      + (1.f - alpha) * (ga0 * hr.y + ga1 * hn.y + ga2 * ht.y);
  *(float2*)(hfused + (size_t)b * 512 + 2 * tid) = o;
}

// ---------------- final LN(enh) + concat-add ----------------
__global__ __launch_bounds__(256) void final_out_kernel(
    const float* __restrict__ epre, const float* __restrict__ enb,
    const float* __restrict__ elng, const float* __restrict__ elnb,
    const float* __restrict__ hcat, float* __restrict__ out)
{
  const int b = blockIdx.x;
  const int tid = threadIdx.x, lane = tid & 63, wave = tid >> 6;
  __shared__ float red[4];
  float2 v;
  {
    float2 p0 = *(const float2*)(epre + (size_t)b * 512 + 2 * tid);
    float2 p1 = *(const float2*)(epre + 262144 + (size_t)b * 512 + 2 * tid);
    float2 bi = *(const float2*)(enb + 2 * tid);
    v.x = p0.x + p1.x + bi.x;
    v.y = p0.y + p1.y + bi.y;
  }
  float s = blk_sum4(v.x + v.y, red, lane, wave);
  float sq = blk_sum4(v.x * v.x + v.y * v.y, red, lane, wave);
  float mean = s * (1.f / 512.f), var = sq * (1.f / 512.f) - mean * mean;
  float rstd = rsqrtf(var + 1e-5f);
  float2 g = *(const float2*)(elng + 2 * tid);
  float2 bb = *(const float2*)(elnb + 2 * tid);
  float e0 = (v.x - mean) * rstd * g.x + bb.x;
  float e1 = (v.y - mean) * rstd * g.y + bb.y;
  const float* hb = hcat + (size_t)b * 1536 + 2 * tid;
  float* ob = out + (size_t)b * 1536 + 2 * tid;
#pragma unroll
  for (int mm = 0; mm < 3; mm++) {
    float2 hv = *(const float2*)(hb + mm * 512);
    *(float2*)(ob + mm * 512) = make_float2(hv.x + e0, hv.y + e1);
  }
}

extern "C" void kernel_launch(void* const* d_in, const int* in_sizes, int n_in,
                              void* d_out, int out_size, void* d_ws, size_t ws_size,
                              hipStream_t stream)
{
  const float* trgb = (const float*)d_in[0];
  const float* tnir = (const float*)d_in[1];
  const float* ttir = (const float*)d_in[2];
  const float* qrgb = (const float*)d_in[3];
  const float* qnir = (const float*)d_in[4];
  const float* qtir = (const float*)d_in[5];
  const float* inw  = (const float*)d_in[6];
  const float* inb  = (const float*)d_in[7];
  const float* outw = (const float*)d_in[8];
  const float* outb = (const float*)d_in[9];
  const float* alng = (const float*)d_in[10];
  const float* alnb = (const float*)d_in[11];
  const float* entw = (const float*)d_in[12];
  const float* entb = (const float*)d_in[13];
  const float* gw1  = (const float*)d_in[14];
  const float* gb1  = (const float*)d_in[15];
  const float* glng = (const float*)d_in[16];
  const float* glnb = (const float*)d_in[17];
  const float* gw2  = (const float*)d_in[18];
  const float* gb2  = (const float*)d_in[19];
  const float* araw = (const float*)d_in[20];
  const float* enw  = (const float*)d_in[21];
  const float* enb  = (const float*)d_in[22];
  const float* elng = (const float*)d_in[23];
  const float* elnb = (const float*)d_in[24];
  float* ws = (float*)d_ws;
  float* out = (float*)d_out;

  hipLaunchKernelGGL(prep_kernel, dim3(4, 8), dim3(256), 0, stream,
                     qrgb, qnir, qtir, inw, inb, entw, entb, ws);
  hipLaunchKernelGGL(attn_pool_kernel, dim3(512, 3), dim3(256), 0, stream,
                     trgb, tnir, ttir, ws, ws + WS_P);
  // vout = P @ Wv^T + bv (batched over 8 heads)
  hipLaunchKernelGGL(gemm_bt_kernel, dim3(24, 1, 8), dim3(256), 0, stream,
                     ws + WS_P, inw + (size_t)1024 * 512, inb + 1024, ws + WS_VOUT,
                     512, 4096, 512, 512,
                     (long)512, (long)64 * 512, (long)64, 64, 1);
  // out2 = vout @ Wo^T + bo
  hipLaunchKernelGGL(gemm_bt_kernel, dim3(24, 8, 1), dim3(256), 0, stream,
                     ws + WS_VOUT, outw, outb, ws + WS_OUT2,
                     512, 512, 512, 512, 0L, 0L, 0L, 0, 1);
  hipLaunchKernelGGL(ln_ent_kernel, dim3(1536), dim3(256), 0, stream,
                     ws + WS_OUT2, alng, alnb, ws, ws + WS_HCAT, ws + WS_H, ws + WS_Z);
  // g_pre partials = hcat @ gate_w1^T (split-K x3, bias added in gate_fuse)
  hipLaunchKernelGGL(gemm_bt_kernel, dim3(8, 8, 3), dim3(256), 0, stream,
                     ws + WS_HCAT, gw1, gb1, ws + WS_GPRE,
                     512, 1536, 1536, 512,
                     (long)512, (long)512, (long)262144, 0, 0);
  hipLaunchKernelGGL(gate_fuse_kernel, dim3(512), dim3(256), 0, stream,
                     ws + WS_GPRE, glng, glnb, gw2, gb2, gb1, araw,
                     ws + WS_HCAT, ws + WS_H, ws + WS_Z, ws + WS_HFUSED);
  // enh partials = h_fused @ enh_w^T (split-K x2, bias added in final_out)
  hipLaunchKernelGGL(gemm_bt_kernel, dim3(8, 8, 2), dim3(256), 0, stream,
                     ws + WS_HFUSED, enw, enb, ws + WS_ENHPRE,
                     256, 512, 512, 512,
                     (long)256, (long)256, (long)262144, 0, 0);
  hipLaunchKernelGGL(final_out_kernel, dim3(512), dim3(256), 0, stream,
                     ws + WS_ENHPRE, enb, elng, elnb, ws + WS_HCAT, out);
}

// Round 9
// 292.214 us; speedup vs baseline: 1.1470x; 1.0093x over previous
//
#include <hip/hip_runtime.h>
#include <cstdint>

// ---------------- workspace layout (float offsets) ----------------
#define WS_U      0                          // 3*8*512 = 12288
#define WS_C0     12288                      // 24 (unused now)
#define WS_ENTBM  12312                      // 1
#define WS_ENTP   12320                      // 8*512 = 4096
#define WS_P      16416                      // 1536*4096 = 6291456
#define WS_OUT2   WS_P                       // alias (P dead after vout GEMM)
#define WS_GPRE   (WS_P + 786432)            // 3 partials * 262144
#define WS_HFUSED (WS_P + 1572864)           // 262144
#define WS_ENHPRE (WS_P + 1835008)           // 2 partials * 262144
#define WS_VOUT   (WS_P + 6291456)           // 786432
#define WS_HCAT   (WS_VOUT + 786432)         // 786432
#define WS_H      (WS_HCAT + 786432)         // 1536
#define WS_Z      (WS_H + 1536)              // 1536

__device__ __forceinline__ float blk_sum4(float v, float* red, int lane, int wave) {
#pragma unroll
  for (int off = 32; off; off >>= 1) v += __shfl_xor(v, off);
  __syncthreads();
  if (lane == 0) red[wave] = v;
  __syncthreads();
  return red[0] + red[1] + red[2] + red[3];
}

// ---------------- prep: grid (4, 8); m<3 -> u vectors, m==3 -> ent partials ----------------
__global__ __launch_bounds__(256) void prep_kernel(
    const float* __restrict__ qrgb, const float* __restrict__ qnir, const float* __restrict__ qtir,
    const float* __restrict__ inw, const float* __restrict__ inb,
    const float* __restrict__ entw, const float* __restrict__ entb,
    float* __restrict__ ws)
{
  const int m = blockIdx.x, h = blockIdx.y;
  const int tid = threadIdx.x, lane = tid & 63, wave = tid >> 6;
  __shared__ float qvl[64];
  __shared__ float red[4];

  if (m == 3) {
    const float* base = entw + (size_t)h * 64 * 512;
    float acc0 = 0.f, acc1 = 0.f;
#pragma unroll 8
    for (int r = 0; r < 64; r++) {
      acc0 += base[(size_t)r * 512 + tid];
      acc1 += base[(size_t)r * 512 + tid + 256];
    }
    ws[WS_ENTP + h * 512 + tid] = acc0;
    ws[WS_ENTP + h * 512 + tid + 256] = acc1;
    return;
  }

  const float* qry = (m == 0) ? qrgb : (m == 1) ? qnir : qtir;
  float4 q0 = *(const float4*)(qry + 4 * lane);
  float4 q1 = *(const float4*)(qry + 256 + 4 * lane);
#pragma unroll 4
  for (int dd = 0; dd < 16; dd++) {
    const int d = wave * 16 + dd;
    const float* wr = inw + (size_t)(h * 64 + d) * 512;
    float4 w0 = *(const float4*)(wr + 4 * lane);
    float4 w1 = *(const float4*)(wr + 256 + 4 * lane);
    float p = w0.x * q0.x + w0.y * q0.y + w0.z * q0.z + w0.w * q0.w
            + w1.x * q1.x + w1.y * q1.y + w1.z * q1.z + w1.w * q1.w;
#pragma unroll
    for (int off = 32; off; off >>= 1) p += __shfl_xor(p, off);
    if (lane == 0) qvl[d] = p + inb[h * 64 + d];
  }
  __syncthreads();
  float acc0 = 0.f, acc1 = 0.f;
  const float* wk = inw + (size_t)(512 + h * 64) * 512;
#pragma unroll 8
  for (int d = 0; d < 64; d++) {
    float qq = qvl[d];
    acc0 = fmaf(qq, wk[(size_t)d * 512 + tid], acc0);
    acc1 = fmaf(qq, wk[(size_t)d * 512 + tid + 256], acc1);
  }
  ws[WS_U + m * 4096 + h * 512 + tid] = 0.125f * acc0;
  ws[WS_U + m * 4096 + h * 512 + tid + 256] = 0.125f * acc1;
  if (m == 0 && h == 0) {
    float v = entb[tid] + entb[tid + 256];
    float s = blk_sum4(v, red, lane, wave);
    if (tid == 0) ws[WS_ENTBM] = s * (1.f / 512.f);
  }
}

// ---------------- attn_pool: lean 3-phase (R6 slimmed) ----------------
// Phase S: verified 4-row batched transpose-reduce butterfly -> raw scores in sc.
// Phase M: verified exact per-head softmax over 129, in place.
// Phase P: R7-pool form -- wave owns 2 heads x ALL rows, acc = 16 regs, direct
//   stores (no lacc, no epilogue barriers). Rows iterated DESCENDING (128->0) so
//   re-reads catch the most L3/L2-recent lines from phase S.
// LDS: 4.2 KB total. Exactly 2 barriers.
__global__ __launch_bounds__(256) void attn_pool_kernel(
    const float* __restrict__ trgb, const float* __restrict__ tnir, const float* __restrict__ ttir,
    const float* __restrict__ ws, float* __restrict__ Pout)
{
  const int b = blockIdx.x, m = blockIdx.y;
  const int tid = threadIdx.x, lane = tid & 63, wave = tid >> 6;
  const float* tok = ((m == 0) ? trgb : (m == 1) ? tnir : ttir) + (size_t)b * 129 * 512;
  const float* u = ws + WS_U + m * 4096;

  __shared__ float sc[8][132];        // raw scores -> softmax weights

  const int b0 = lane & 1, b1 = (lane >> 1) & 1, b2 = (lane >> 2) & 1;
  const int b3 = (lane >> 3) & 1, b4 = (lane >> 4) & 1;
  const int r_own = (b0 << 1) | b1;
  const int h_own = (b2 << 2) | (b3 << 1) | b4;
  const int wbase = wave * 32;

#define LOADB(L0, A0, C0, A1, C1, A2, C2, A3, C3)                         \
  do {                                                                    \
    int r0_ = (L0), r1_ = (L0) + 1, r2_ = (L0) + 2, r3_ = (L0) + 3;       \
    if (r1_ > 128) r1_ = 128;                                             \
    if (r2_ > 128) r2_ = 128;                                             \
    if (r3_ > 128) r3_ = 128;                                             \
    const float* p0_ = tok + (size_t)r0_ * 512 + 4 * lane;                \
    const float* p1_ = tok + (size_t)r1_ * 512 + 4 * lane;                \
    const float* p2_ = tok + (size_t)r2_ * 512 + 4 * lane;                \
    const float* p3_ = tok + (size_t)r3_ * 512 + 4 * lane;                \
    A0 = *(const float4*)p0_; C0 = *(const float4*)(p0_ + 256);           \
    A1 = *(const float4*)p1_; C1 = *(const float4*)(p1_ + 256);           \
    A2 = *(const float4*)p2_; C2 = *(const float4*)(p2_ + 256);           \
    A3 = *(const float4*)p3_; C3 = *(const float4*)(p3_ + 256);           \
  } while (0)

  // by-value float4 params (SROA-safe, R1/R7 precedent)
  auto score_batch = [&](int l0, bool tail,
                         float4 A0, float4 C0, float4 A1, float4 C1,
                         float4 A2, float4 C2, float4 A3, float4 C3) {
    float x[32];
#pragma unroll
    for (int h = 0; h < 8; h++) {
      float4 U0 = *(const float4*)(u + h * 512 + 4 * lane);
      float4 U1 = *(const float4*)(u + h * 512 + 256 + 4 * lane);
      x[h]      = A0.x * U0.x + A0.y * U0.y + A0.z * U0.z + A0.w * U0.w
                + C0.x * U1.x + C0.y * U1.y + C0.z * U1.z + C0.w * U1.w;
      x[8 + h]  = A1.x * U0.x + A1.y * U0.y + A1.z * U0.z + A1.w * U0.w
                + C1.x * U1.x + C1.y * U1.y + C1.z * U1.z + C1.w * U1.w;
      x[16 + h] = A2.x * U0.x + A2.y * U0.y + A2.z * U0.z + A2.w * U0.w
                + C2.x * U1.x + C2.y * U1.y + C2.z * U1.z + C2.w * U1.w;
      x[24 + h] = A3.x * U0.x + A3.y * U0.y + A3.z * U0.z + A3.w * U0.w
                + C3.x * U1.x + C3.y * U1.y + C3.z * U1.z + C3.w * U1.w;
    }
    // transpose-reduce butterfly (verified R4/R6/R7): one 6-deep chain for all 32
#define MERGE_STAGE(n, M, bit)                                  \
    _Pragma("unroll")                                           \
    for (int j = 0; j < (n) / 2; j++) {                         \
      float keep = (bit) ? x[j + (n) / 2] : x[j];               \
      float send = (bit) ? x[j] : x[j + (n) / 2];               \
      x[j] = keep + __shfl_xor(send, (M));                      \
    }
    MERGE_STAGE(32, 1, b0)
    MERGE_STAGE(16, 2, b1)
    MERGE_STAGE(8, 4, b2)
    MERGE_STAGE(4, 8, b3)
    MERGE_STAGE(2, 16, b4)
#undef MERGE_STAGE
    float T = x[0] + __shfl_xor(x[0], 32);   // lane holds score of (r_own, h_own)
    if (lane < 32 && (!tail || r_own == 0))
      sc[h_own][l0 + r_own] = T;             // write-only; no roundtrip
  };

  // ---- phase S: scores, 8 batches of 4 rows, 1-batch-ahead prefetch ----
  {
    float4 A0, C0, A1, C1, A2, C2, A3, C3;
    float4 N0, D0, N1, D1, N2, D2, N3, D3;
    LOADB(wbase, A0, C0, A1, C1, A2, C2, A3, C3);
    for (int bt = 0; bt < 8; bt++) {
      if (bt < 7) LOADB(wbase + 4 * bt + 4, N0, D0, N1, D1, N2, D2, N3, D3);
      score_batch(wbase + 4 * bt, false, A0, C0, A1, C1, A2, C2, A3, C3);
      A0 = N0; C0 = D0; A1 = N1; C1 = D1;
      A2 = N2; C2 = D2; A3 = N3; C3 = D3;
    }
    if (wave == 0) {   // row 128: clamped batch, only r_own==0 written
      LOADB(128, A0, C0, A1, C1, A2, C2, A3, C3);
      score_batch(128, true, A0, C0, A1, C1, A2, C2, A3, C3);
    }
  }
#undef LOADB
  __syncthreads();

  // ---- phase M: exact per-head softmax over 129 (verified), in place ----
#pragma unroll
  for (int hh = 0; hh < 2; hh++) {
    const int h = wave * 2 + hh;
    float x0 = sc[h][lane];
    float x1 = sc[h][64 + lane];
    float x2 = (lane == 0) ? sc[h][128] : -3.0e38f;
    float mx = fmaxf(fmaxf(x0, x1), x2);
#pragma unroll
    for (int off = 32; off; off >>= 1) mx = fmaxf(mx, __shfl_xor(mx, off));
    float e0 = __expf(x0 - mx), e1 = __expf(x1 - mx);
    float e2 = (lane == 0) ? __expf(x2 - mx) : 0.f;
    float s = e0 + e1 + e2;
#pragma unroll
    for (int off = 32; off; off >>= 1) s += __shfl_xor(s, off);
    float inv = 1.f / s;
    sc[h][lane] = e0 * inv;
    sc[h][64 + lane] = e1 * inv;
    if (lane == 0) sc[h][128] = e2 * inv;
  }
  __syncthreads();

  // ---- phase P: wave owns 2 heads x all rows, DESCENDING (L3-recency) ----
  const int h0 = wave * 2, h1 = h0 + 1;
  float4 acc00 = make_float4(0.f, 0.f, 0.f, 0.f);
  float4 acc01 = make_float4(0.f, 0.f, 0.f, 0.f);
  float4 acc10 = make_float4(0.f, 0.f, 0.f, 0.f);
  float4 acc11 = make_float4(0.f, 0.f, 0.f, 0.f);

#define LDROW(rr, Av, Cv)                                         \
  do {                                                            \
    const float* p_ = tok + (size_t)(rr) * 512 + 4 * lane;        \
    Av = *(const float4*)p_; Cv = *(const float4*)(p_ + 256);     \
  } while (0)

#define POOLR(Av, Cv, l)                                          \
  do {                                                            \
    float w0_ = sc[h0][l], w1_ = sc[h1][l];                       \
    acc00.x = fmaf(w0_, Av.x, acc00.x);                           \
    acc00.y = fmaf(w0_, Av.y, acc00.y);                           \
    acc00.z = fmaf(w0_, Av.z, acc00.z);                           \
    acc00.w = fmaf(w0_, Av.w, acc00.w);                           \
    acc01.x = fmaf(w0_, Cv.x, acc01.x);                           \
    acc01.y = fmaf(w0_, Cv.y, acc01.y);                           \
    acc01.z = fmaf(w0_, Cv.z, acc01.z);                           \
    acc01.w = fmaf(w0_, Cv.w, acc01.w);                           \
    acc10.x = fmaf(w1_, Av.x, acc10.x);                           \
    acc10.y = fmaf(w1_, Av.y, acc10.y);                           \
    acc10.z = fmaf(w1_, Av.z, acc10.z);                           \
    acc10.w = fmaf(w1_, Av.w, acc10.w);                           \
    acc11.x = fmaf(w1_, Cv.x, acc11.x);                           \
    acc11.y = fmaf(w1_, Cv.y, acc11.y);                           \
    acc11.z = fmaf(w1_, Cv.z, acc11.z);                           \
    acc11.w = fmaf(w1_, Cv.w, acc11.w);                           \
  } while (0)

  {
    float4 A0, C0, A1, C1, A2, C2, A3, C3;
    // descending ring: rows 128,127,...,1 in 32 groups of 4, then row 0
    LDROW(128, A0, C0); LDROW(127, A1, C1); LDROW(126, A2, C2); LDROW(125, A3, C3);
    for (int g = 0; g < 32; g++) {
      const int rb = 128 - 4 * g;
      int rr;
      POOLR(A0, C0, rb);
      rr = rb - 4; if (rr < 0) rr = 0; LDROW(rr, A0, C0);
      POOLR(A1, C1, rb - 1);
      rr = rb - 5; if (rr < 0) rr = 0; LDROW(rr, A1, C1);
      POOLR(A2, C2, rb - 2);
      rr = rb - 6; if (rr < 0) rr = 0; LDROW(rr, A2, C2);
      POOLR(A3, C3, rb - 3);
      rr = rb - 7; if (rr < 0) rr = 0; LDROW(rr, A3, C3);
    }
    POOLR(A0, C0, 0);   // A0 holds row 0 (loaded at g=31, stage 0)
  }
#undef LDROW
#undef POOLR

  // direct store: wave writes its 2 heads (no cross-wave combine needed)
  float* prow = Pout + (size_t)(m * 512 + b) * 4096;
  *(float4*)(prow + h0 * 512 + 4 * lane) = acc00;
  *(float4*)(prow + h0 * 512 + 256 + 4 * lane) = acc01;
  *(float4*)(prow + h1 * 512 + 4 * lane) = acc10;
  *(float4*)(prow + h1 * 512 + 256 + 4 * lane) = acc11;
}

// ---------------- f32 GEMM: C = A @ B^T (+bias), 64x64 tile, 4x4 micro ----------------
__global__ __launch_bounds__(256) void gemm_bt_kernel(
    const float* __restrict__ A, const float* __restrict__ B,
    const float* __restrict__ bias, float* __restrict__ C,
    int K, int lda, int ldb, int ldc,
    long sA, long sB, long sC, int sBias, int addBias)
{
  A += (long)blockIdx.z * sA;
  B += (long)blockIdx.z * sB;
  C += (long)blockIdx.z * sC;
  const float* bp = bias + (long)blockIdx.z * sBias;
  __shared__ float As[32][68];
  __shared__ float Bs[32][68];
  const int tid = threadIdx.x;
  const int tx = tid & 15, ty = tid >> 4;
  const int rowL = tid >> 3;
  const int colv = (tid & 7) << 2;
  const int m0 = blockIdx.x * 64, n0 = blockIdx.y * 64;
  float acc[4][4] = {};
  for (int k0 = 0; k0 < K; k0 += 32) {
#pragma unroll
    for (int it = 0; it < 2; it++) {
      const int r = rowL + it * 32;
      float4 v = *(const float4*)(A + (size_t)(m0 + r) * lda + k0 + colv);
      As[colv + 0][r] = v.x; As[colv + 1][r] = v.y; As[colv + 2][r] = v.z; As[colv + 3][r] = v.w;
      float4 w = *(const float4*)(B + (size_t)(n0 + r) * ldb + k0 + colv);
      Bs[colv + 0][r] = w.x; Bs[colv + 1][r] = w.y; Bs[colv + 2][r] = w.z; Bs[colv + 3][r] = w.w;
    }
    __syncthreads();
#pragma unroll
    for (int k = 0; k < 32; k++) {
      float4 a4 = *(const float4*)&As[k][ty * 4];
      float4 b4 = *(const float4*)&Bs[k][tx * 4];
      acc[0][0] += a4.x * b4.x; acc[0][1] += a4.x * b4.y; acc[0][2] += a4.x * b4.z; acc[0][3] += a4.x * b4.w;
      acc[1][0] += a4.y * b4.x; acc[1][1] += a4.y * b4.y; acc[1][2] += a4.y * b4.z; acc[1][3] += a4.y * b4.w;
      acc[2][0] += a4.z * b4.x; acc[2][1] += a4.z * b4.y; acc[2][2] += a4.z * b4.z; acc[2][3] += a4.z * b4.w;
      acc[3][0] += a4.w * b4.x; acc[3][1] += a4.w * b4.y; acc[3][2] += a4.w * b4.z; acc[3][3] += a4.w * b4.w;
    }
    __syncthreads();
  }
  float4 bv = make_float4(0.f, 0.f, 0.f, 0.f);
  if (addBias) bv = *(const float4*)(bp + n0 + tx * 4);
#pragma unroll
  for (int i = 0; i < 4; i++) {
    float4 o;
    o.x = acc[i][0] + bv.x; o.y = acc[i][1] + bv.y;
    o.z = acc[i][2] + bv.z; o.w = acc[i][3] + bv.w;
    *(float4*)(C + (size_t)(m0 + ty * 4 + i) * ldc + n0 + tx * 4) = o;
  }
}

// ---------------- LN(attn out) + entropy + z ----------------
__global__ __launch_bounds__(256) void ln_ent_kernel(
    const float* __restrict__ out2,
    const float* __restrict__ lng, const float* __restrict__ lnb,
    const float* __restrict__ ws, float* __restrict__ hcat,
    float* __restrict__ Hout, float* __restrict__ zout)
{
  const int r = blockIdx.x;
  const int mod = r >> 9, b = r & 511;
  const int tid = threadIdx.x, lane = tid & 63, wave = tid >> 6;
  __shared__ float red[4];
  const float* x = out2 + (size_t)r * 512;
  float2 v = *(const float2*)(x + 2 * tid);
  float s = blk_sum4(v.x + v.y, red, lane, wave);
  float sq = blk_sum4(v.x * v.x + v.y * v.y, red, lane, wave);
  float mean = s * (1.f / 512.f);
  float var = sq * (1.f / 512.f) - mean * mean;
  float rstd = rsqrtf(var + 1e-5f);
  float2 g = *(const float2*)(lng + 2 * tid);
  float2 bb = *(const float2*)(lnb + 2 * tid);
  float h0 = (v.x - mean) * rstd * g.x + bb.x;
  float h1 = (v.y - mean) * rstd * g.y + bb.y;
  *(float2*)(hcat + (size_t)b * 1536 + mod * 512 + 2 * tid) = make_float2(h0, h1);
  float2 ep = make_float2(0.f, 0.f);
#pragma unroll
  for (int j = 0; j < 8; j++) {
    float2 t = *(const float2*)(ws + WS_ENTP + j * 512 + 2 * tid);
    ep.x += t.x; ep.y += t.y;
  }
  ep.x *= (1.f / 512.f); ep.y *= (1.f / 512.f);
  float fa0 = fabsf(h0) + 1e-8f, fa1 = fabsf(h1) + 1e-8f;
  float S = blk_sum4(fa0 + fa1, red, lane, wave);
  float zz = blk_sum4(h0 * ep.x + h1 * ep.y, red, lane, wave);
  float invS = 1.f / S;
  float p0 = fa0 * invS, p1 = fa1 * invS;
  float t = blk_sum4(p0 * logf(p0 + 1e-8f) + p1 * logf(p1 + 1e-8f), red, lane, wave);
  if (tid == 0) {
    Hout[mod * 512 + b] = -t;
    zout[mod * 512 + b] = zz + ws[WS_ENTBM];
  }
}

// ---------------- gate LN/relu/sigmoid + entropy softmax + fuse ----------------
__global__ __launch_bounds__(256) void gate_fuse_kernel(
    const float* __restrict__ gpre, const float* __restrict__ glng, const float* __restrict__ glnb,
    const float* __restrict__ gw2, const float* __restrict__ gb2, const float* __restrict__ gb1,
    const float* __restrict__ araw, const float* __restrict__ hcat,
    const float* __restrict__ H, const float* __restrict__ z,
    float* __restrict__ hfused)
{
  const int b = blockIdx.x;
  const int tid = threadIdx.x, lane = tid & 63, wave = tid >> 6;
  __shared__ float red[4];
  float2 v;
  {
    float2 p0 = *(const float2*)(gpre + (size_t)b * 512 + 2 * tid);
    float2 p1 = *(const float2*)(gpre + 262144 + (size_t)b * 512 + 2 * tid);
    float2 p2 = *(const float2*)(gpre + 524288 + (size_t)b * 512 + 2 * tid);
    float2 bi = *(const float2*)(gb1 + 2 * tid);
    v.x = p0.x + p1.x + p2.x + bi.x;
    v.y = p0.y + p1.y + p2.y + bi.y;
  }
  float s = blk_sum4(v.x + v.y, red, lane, wave);
  float sq = blk_sum4(v.x * v.x + v.y * v.y, red, lane, wave);
  float mean = s * (1.f / 512.f), var = sq * (1.f / 512.f) - mean * mean;
  float rstd = rsqrtf(var + 1e-5f);
  float2 g = *(const float2*)(glng + 2 * tid);
  float2 bb = *(const float2*)(glnb + 2 * tid);
  float g0 = fmaxf((v.x - mean) * rstd * g.x + bb.x, 0.f);
  float g1 = fmaxf((v.y - mean) * rstd * g.y + bb.y, 0.f);
  float d0 = blk_sum4(g0 * gw2[2 * tid] + g1 * gw2[2 * tid + 1], red, lane, wave);
  float d1 = blk_sum4(g0 * gw2[512 + 2 * tid] + g1 * gw2[512 + 2 * tid + 1], red, lane, wave);
  float d2 = blk_sum4(g0 * gw2[1024 + 2 * tid] + g1 * gw2[1024 + 2 * tid + 1], red, lane, wave);
  float ga0 = 1.f / (1.f + __expf(-(d0 + gb2[0])));
  float ga1 = 1.f / (1.f + __expf(-(d1 + gb2[1])));
  float ga2 = 1.f / (1.f + __expf(-(d2 + gb2[2])));
  float sc0 = z[b] * __expf(-H[b]);
  float sc1 = z[512 + b] * __expf(-H[512 + b]);
  float sc2 = z[1024 + b] * __expf(-H[1024 + b]);
  float mxs = fmaxf(sc0, fmaxf(sc1, sc2));
  float e0 = __expf(sc0 - mxs), e1 = __expf(sc1 - mxs), e2 = __expf(sc2 - mxs);
  float inv = 1.f / (e0 + e1 + e2);
  e0 *= inv; e1 *= inv; e2 *= inv;
  float alpha = 1.f / (1.f + __expf(-araw[0]));
  const float* hb = hcat + (size_t)b * 1536 + 2 * tid;
  float2 hr = *(const float2*)hb;
  float2 hn = *(const float2*)(hb + 512);
  float2 ht = *(const float2*)(hb + 1024);
  float2 o;
  o.x = alpha * (e0 * hr.x + e1 * hn.x + e2 * ht.x)
      + (1.f - alpha) * (ga0 * hr.x + ga1 * hn.x + ga2 * ht.x);
  o.y = alpha * (e0 * hr.y + e1 * hn.y + e2 * ht.y)
      + (1.f - alpha) * (ga0 * hr.y + ga1 * hn.y + ga2 * ht.y);
  *(float2*)(hfused + (size_t)b * 512 + 2 * tid) = o;
}

// ---------------- final LN(enh) + concat-add ----------------
__global__ __launch_bounds__(256) void final_out_kernel(
    const float* __restrict__ epre, const float* __restrict__ enb,
    const float* __restrict__ elng, const float* __restrict__ elnb,
    const float* __restrict__ hcat, float* __restrict__ out)
{
  const int b = blockIdx.x;
  const int tid = threadIdx.x, lane = tid & 63, wave = tid >> 6;
  __shared__ float red[4];
  float2 v;
  {
    float2 p0 = *(const float2*)(epre + (size_t)b * 512 + 2 * tid);
    float2 p1 = *(const float2*)(epre + 262144 + (size_t)b * 512 + 2 * tid);
    float2 bi = *(const float2*)(enb + 2 * tid);
    v.x = p0.x + p1.x + bi.x;
    v.y = p0.y + p1.y + bi.y;
  }
  float s = blk_sum4(v.x + v.y, red, lane, wave);
  float sq = blk_sum4(v.x * v.x + v.y * v.y, red, lane, wave);
  float mean = s * (1.f / 512.f), var = sq * (1.f / 512.f) - mean * mean;
  float rstd = rsqrtf(var + 1e-5f);
  float2 g = *(const float2*)(elng + 2 * tid);
  float2 bb = *(const float2*)(elnb + 2 * tid);
  float e0 = (v.x - mean) * rstd * g.x + bb.x;
  float e1 = (v.y - mean) * rstd * g.y + bb.y;
  const float* hb = hcat + (size_t)b * 1536 + 2 * tid;
  float* ob = out + (size_t)b * 1536 + 2 * tid;
#pragma unroll
  for (int mm = 0; mm < 3; mm++) {
    float2 hv = *(const float2*)(hb + mm * 512);
    *(float2*)(ob + mm * 512) = make_float2(hv.x + e0, hv.y + e1);
  }
}

extern "C" void kernel_launch(void* const* d_in, const int* in_sizes, int n_in,
                              void* d_out, int out_size, void* d_ws, size_t ws_size,
                              hipStream_t stream)
{
  const float* trgb = (const float*)d_in[0];
  const float* tnir = (const float*)d_in[1];
  const float* ttir = (const float*)d_in[2];
  const float* qrgb = (const float*)d_in[3];
  const float* qnir = (const float*)d_in[4];
  const float* qtir = (const float*)d_in[5];
  const float* inw  = (const float*)d_in[6];
  const float* inb  = (const float*)d_in[7];
  const float* outw = (const float*)d_in[8];
  const float* outb = (const float*)d_in[9];
  const float* alng = (const float*)d_in[10];
  const float* alnb = (const float*)d_in[11];
  const float* entw = (const float*)d_in[12];
  const float* entb = (const float*)d_in[13];
  const float* gw1  = (const float*)d_in[14];
  const float* gb1  = (const float*)d_in[15];
  const float* glng = (const float*)d_in[16];
  const float* glnb = (const float*)d_in[17];
  const float* gw2  = (const float*)d_in[18];
  const float* gb2  = (const float*)d_in[19];
  const float* araw = (const float*)d_in[20];
  const float* enw  = (const float*)d_in[21];
  const float* enb  = (const float*)d_in[22];
  const float* elng = (const float*)d_in[23];
  const float* elnb = (const float*)d_in[24];
  float* ws = (float*)d_ws;
  float* out = (float*)d_out;

  hipLaunchKernelGGL(prep_kernel, dim3(4, 8), dim3(256), 0, stream,
                     qrgb, qnir, qtir, inw, inb, entw, entb, ws);
  hipLaunchKernelGGL(attn_pool_kernel, dim3(512, 3), dim3(256), 0, stream,
                     trgb, tnir, ttir, ws, ws + WS_P);
  // vout = P @ Wv^T + bv (batched over 8 heads)
  hipLaunchKernelGGL(gemm_bt_kernel, dim3(24, 1, 8), dim3(256), 0, stream,
                     ws + WS_P, inw + (size_t)1024 * 512, inb + 1024, ws + WS_VOUT,
                     512, 4096, 512, 512,
                     (long)512, (long)64 * 512, (long)64, 64, 1);
  // out2 = vout @ Wo^T + bo
  hipLaunchKernelGGL(gemm_bt_kernel, dim3(24, 8, 1), dim3(256), 0, stream,
                     ws + WS_VOUT, outw, outb, ws + WS_OUT2,
                     512, 512, 512, 512, 0L, 0L, 0L, 0, 1);
  hipLaunchKernelGGL(ln_ent_kernel, dim3(1536), dim3(256), 0, stream,
                     ws + WS_OUT2, alng, alnb, ws, ws + WS_HCAT, ws + WS_H, ws + WS_Z);
  // g_pre partials = hcat @ gate_w1^T (split-K x3, bias added in gate_fuse)
  hipLaunchKernelGGL(gemm_bt_kernel, dim3(8, 8, 3), dim3(256), 0, stream,
                     ws + WS_HCAT, gw1, gb1, ws + WS_GPRE,
                     512, 1536, 1536, 512,
                     (long)512, (long)512, (long)262144, 0, 0);
  hipLaunchKernelGGL(gate_fuse_kernel, dim3(512), dim3(256), 0, stream,
                     ws + WS_GPRE, glng, glnb, gw2, gb2, gb1, araw,
                     ws + WS_HCAT, ws + WS_H, ws + WS_Z, ws + WS_HFUSED);
  // enh partials = h_fused @ enh_w^T (split-K x2, bias added in final_out)
  hipLaunchKernelGGL(gemm_bt_kernel, dim3(8, 8, 2), dim3(256), 0, stream,
                     ws + WS_HFUSED, enw, enb, ws + WS_ENHPRE,
                     256, 512, 512, 512,
                     (long)256, (long)256, (long)262144, 0, 0);
  hipLaunchKernelGGL(final_out_kernel, dim3(512), dim3(256), 0, stream,
                     ws + WS_ENHPRE, enb, elng, elnb, ws + WS_HCAT, out);
}